// Round 4
// baseline (117574.695 us; speedup 1.0000x reference)
//
#include <hip/hip_runtime.h>
#include <hip/hip_bf16.h>
#include <hip/hip_cooperative_groups.h>

namespace cg = cooperative_groups;

typedef __attribute__((ext_vector_type(8))) _Float16 half8_t;
typedef __attribute__((ext_vector_type(4))) float f32x4_t;

#define S0W 1544                    // LDS row stride (elems): 1536 + 8 pad
#define LDS_BYTES (32 * S0W * 2)    // 98816 B (W0 plane-1 only)

__device__ __forceinline__ float sigm(float z) { return 1.0f / (1.0f + __expf(-z)); }
__device__ __forceinline__ float tanh_fast(float z) {
  float e = __expf(2.0f * z);
  return 1.0f - 2.0f / (e + 1.0f);
}

// ws layout (bytes) — IDENTICAL footprint to round 2 (known-good 60,395,520 B):
//   W0a @ 0         : 12582912   (fp16 plane1 = fp16(32*w), [gp][k])
//   W0b @ 12582912  : 12582912   (fp16 plane2 = fp16((32w - p1)*2048))
//   W1a @ 25165824  : 16777216
//   W1b @ 41943040  : 16777216
//   vecs@ 58720256  : 98304      (b0,g0,be0,b1,g1,be1 permuted, fp32)
//   hch @ 58818560  : 524288     (h plane1 fp16, [row][h0|h1])
//   hcm @ 59342848  : 524288     (h plane2 fp16, residual*2048)
//   stats@59867136  : 4096
//   h1f32@59871232  : 524288

// permutation: gp = colgrp*32 + c ; tile=c>>4, cc=c&15, gate=cc>>2, uo=cc&3
//              gcol = gate*1024 + colgrp*8 + tile*4 + uo
__global__ void lstm_prep(const float* __restrict__ W0, const float* __restrict__ W1,
                          const float* __restrict__ b0, const float* __restrict__ g0,
                          const float* __restrict__ be0, const float* __restrict__ b1,
                          const float* __restrict__ g1, const float* __restrict__ be1,
                          _Float16* __restrict__ W0a, _Float16* __restrict__ W0b,
                          _Float16* __restrict__ W1a, _Float16* __restrict__ W1b,
                          float* __restrict__ vecs)
{
  int gid = blockIdx.x * 256 + threadIdx.x;
  const int W0N = 192 * 4096;
  const int W1N = 256 * 4096;
  if (gid < W0N) {
    int k8 = gid >> 12, gp = gid & 4095;
    int colgrp = gp >> 5, c = gp & 31;
    int tile = c >> 4, cc = c & 15;
    int gcol = ((cc >> 2) << 10) + (colgrp << 3) + (tile << 2) + (cc & 3);
    half8_t va, vb;
    #pragma unroll
    for (int j = 0; j < 8; ++j) {
      float w32 = W0[(size_t)(k8 * 8 + j) * 4096 + gcol] * 32.0f;
      _Float16 p1 = (_Float16)w32;
      float r = w32 - (float)p1;
      va[j] = p1; vb[j] = (_Float16)(r * 2048.0f);
    }
    *(half8_t*)&W0a[(size_t)gp * 1536 + k8 * 8] = va;
    *(half8_t*)&W0b[(size_t)gp * 1536 + k8 * 8] = vb;
  } else if (gid < W0N + W1N) {
    int g2 = gid - W0N;
    int k8 = g2 >> 12, gp = g2 & 4095;
    int colgrp = gp >> 5, c = gp & 31;
    int tile = c >> 4, cc = c & 15;
    int gcol = ((cc >> 2) << 10) + (colgrp << 3) + (tile << 2) + (cc & 3);
    half8_t va, vb;
    #pragma unroll
    for (int j = 0; j < 8; ++j) {
      float w32 = W1[(size_t)(k8 * 8 + j) * 4096 + gcol] * 32.0f;
      _Float16 p1 = (_Float16)w32;
      float r = w32 - (float)p1;
      va[j] = p1; vb[j] = (_Float16)(r * 2048.0f);
    }
    *(half8_t*)&W1a[(size_t)gp * 2048 + k8 * 8] = va;
    *(half8_t*)&W1b[(size_t)gp * 2048 + k8 * 8] = vb;
  } else if (gid < W0N + W1N + 6 * 4096) {
    int g2 = gid - W0N - W1N;
    int j = g2 >> 12, gp = g2 & 4095;
    int colgrp = gp >> 5, c = gp & 31;
    int tile = c >> 4, cc = c & 15;
    int gcol = ((cc >> 2) << 10) + (colgrp << 3) + (tile << 2) + (cc & 3);
    const float* src = (j == 0) ? b0 : (j == 1) ? g0 : (j == 2) ? be0
                     : (j == 3) ? b1 : (j == 4) ? g1 : be1;
    vecs[j * 4096 + gp] = src[gcol];
  }
}

#define MFMA16(A, B, C) __builtin_amdgcn_mfma_f32_16x16x32_f16(A, B, C, 0, 0, 0)

// persistent cooperative kernel: 256 WGs (128 colgrps x 2 m-halves) x 256 thr
__global__ void __launch_bounds__(256, 1) lstm_seq(
    const float* __restrict__ x,
    const _Float16* __restrict__ W0ap,
    const _Float16* __restrict__ W0bp,
    const _Float16* __restrict__ W1ap,
    const _Float16* __restrict__ W1bp,
    const float* __restrict__ vecs,
    _Float16* __restrict__ hch,
    _Float16* __restrict__ hcm,
    float* __restrict__ stats,
    float* __restrict__ h1f32,
    const float* __restrict__ fcW,
    const float* __restrict__ fcb,
    float* __restrict__ out)
{
  extern __shared__ _Float16 W0s[];   // [32][S0W] plane-1 (scaled x32)
  const int tid = threadIdx.x;
  const int wgid = blockIdx.x;
  const int colgrp = wgid & 127;
  const int mhalf = wgid >> 7;
  const int wid = tid >> 6;
  const int lane = tid & 63;
  const int c16 = lane & 15;
  const int klo = lane >> 4;

  // stage this colgrp's W0 plane-1 slice (32 cols x 1536 k) into LDS, once
  for (int i = tid; i < 32 * 192; i += 256) {
    int r = i / 192, ch = i - r * 192;
    *(half8_t*)&W0s[r * S0W + ch * 8] =
        *(const half8_t*)&W0ap[((size_t)colgrp * 32 + r) * 1536 + ch * 8];
  }
  __syncthreads();

  float b0c[2], g0c[2], be0c[2], b1c[2], g1c[2], be1c[2];
  #pragma unroll
  for (int tl = 0; tl < 2; ++tl) {
    int gp = colgrp * 32 + tl * 16 + c16;
    b0c[tl]  = vecs[gp];
    g0c[tl]  = vecs[4096 + gp];
    be0c[tl] = vecs[8192 + gp];
    b1c[tl]  = vecs[12288 + gp];
    g1c[tl]  = vecs[16384 + gp];
    be1c[tl] = vecs[20480 + gp];
  }

  const int mtile = mhalf * 4 + wid;                 // 0..7
  const int arow = mtile * 16 + c16;                 // batch row this lane loads for A-frags
  const float* xbase = x + (size_t)arow * 512 * 512; // x[row][t][d]
  const _Float16* hrh = hch + arow * 2048;
  const _Float16* hrm = hcm + arow * 2048;
  const _Float16* w0m0 = W0bp + (size_t)(colgrp * 32 + c16) * 1536;
  const _Float16* w0m1 = w0m0 + (size_t)16 * 1536;
  const _Float16* w1a0 = W1ap + (size_t)(colgrp * 32 + c16) * 2048;
  const _Float16* w1a1 = w1a0 + (size_t)16 * 2048;
  const _Float16* w1b0 = W1bp + (size_t)(colgrp * 32 + c16) * 2048;
  const _Float16* w1b1 = w1b0 + (size_t)16 * 2048;

  float c0s[2][4] = {{0,0,0,0},{0,0,0,0}};
  float c1s[2][4] = {{0,0,0,0},{0,0,0,0}};

  cg::grid_group grid = cg::this_grid();

#define SPLIT2(E, J) { float e_ = (E); _Float16 h1_ = (_Float16)e_;           \
  float r_ = e_ - (float)h1_; ah[J] = h1_; am[J] = (_Float16)(r_ * 2048.0f); }

// products kept: a1*b1 (HH chains), a1*b2 + a2*b1 (MID chains); a2*b2 dropped (2^-22)
#define PROD6(H0A, H1A, M0A, M1A) \
  H0A = MFMA16(ah, bh0, H0A); H1A = MFMA16(ah, bh1, H1A);                     \
  M0A = MFMA16(ah, bm0, M0A); M1A = MFMA16(ah, bm1, M1A);                     \
  M0A = MFMA16(am, bh0, M0A); M1A = MFMA16(am, bh1, M1A);

  for (int t = 0; t < 512; ++t) {
    const int par = t & 1;
    const int npar = 1 - par;

    // ========= A0: gates0 = [x_t, h0] @ W0slice (2-plane fp16 split) ========
    f32x4_t a0he = {0,0,0,0}, a0ho = {0,0,0,0}, a1he = {0,0,0,0}, a1ho = {0,0,0,0};
    f32x4_t a0me = {0,0,0,0}, a0mo = {0,0,0,0}, a1me = {0,0,0,0}, a1mo = {0,0,0,0};
    {
      const float* xp = xbase + t * 512 + klo * 8;

#define X_BODY(KB, H0A, H1A, M0A, M1A) {                                      \
      float4 xu = *(const float4*)(xp + (KB) * 32);                           \
      float4 xw = *(const float4*)(xp + (KB) * 32 + 4);                       \
      half8_t ah, am;                                                         \
      SPLIT2(xu.x, 0) SPLIT2(xu.y, 1) SPLIT2(xu.z, 2) SPLIT2(xu.w, 3)         \
      SPLIT2(xw.x, 4) SPLIT2(xw.y, 5) SPLIT2(xw.z, 6) SPLIT2(xw.w, 7)         \
      half8_t bh0 = *(const half8_t*)&W0s[c16 * S0W + (KB) * 32 + klo * 8];   \
      half8_t bh1 = *(const half8_t*)&W0s[(16 + c16) * S0W + (KB) * 32 + klo * 8]; \
      half8_t bm0 = *(const half8_t*)&w0m0[(KB) * 32 + klo * 8];              \
      half8_t bm1 = *(const half8_t*)&w0m1[(KB) * 32 + klo * 8];              \
      PROD6(H0A, H1A, M0A, M1A) }

      #pragma unroll 2
      for (int kb = 0; kb < 16; kb += 2) {
        X_BODY(kb,     a0he, a1he, a0me, a1me);
        X_BODY(kb + 1, a0ho, a1ho, a0mo, a1mo);
      }
#undef X_BODY

#define H0_BODY(KB, H0A, H1A, M0A, M1A) {                                     \
      half8_t ah = *(const half8_t*)&hrh[(KB) * 32 + klo * 8];                \
      half8_t am = *(const half8_t*)&hrm[(KB) * 32 + klo * 8];                \
      half8_t bh0 = *(const half8_t*)&W0s[c16 * S0W + 512 + (KB) * 32 + klo * 8]; \
      half8_t bh1 = *(const half8_t*)&W0s[(16 + c16) * S0W + 512 + (KB) * 32 + klo * 8]; \
      half8_t bm0 = *(const half8_t*)&w0m0[512 + (KB) * 32 + klo * 8];        \
      half8_t bm1 = *(const half8_t*)&w0m1[512 + (KB) * 32 + klo * 8];        \
      PROD6(H0A, H1A, M0A, M1A) }

      #pragma unroll 2
      for (int kb = 0; kb < 32; kb += 2) {
        H0_BODY(kb,     a0he, a1he, a0me, a1me);
        H0_BODY(kb + 1, a0ho, a1ho, a0mo, a1mo);
      }
#undef H0_BODY
    }
    // combine: z = acc_hh/32 + acc_mid/(32*2048)
    f32x4_t a0 = (a0he + a0ho) * 0.03125f + (a0me + a0mo) * (1.0f / 65536.0f);
    f32x4_t a1 = (a1he + a1ho) * 0.03125f + (a1me + a1mo) * (1.0f / 65536.0f);
    #pragma unroll
    for (int r = 0; r < 4; ++r) { a0[r] += b0c[0]; a1[r] += b0c[1]; }
    // LN partial sums -> atomics (one lane per 16-group per row)
    #pragma unroll
    for (int r = 0; r < 4; ++r) {
      float s = a0[r] + a1[r];
      float q = a0[r]*a0[r] + a1[r]*a1[r];
      #pragma unroll
      for (int m = 1; m <= 8; m <<= 1) { s += __shfl_xor(s, m); q += __shfl_xor(q, m); }
      if (c16 == 0) {
        int row = mtile * 16 + klo * 4 + r;
        atomicAdd(&stats[par * 256 + row * 2 + 0], s);
        atomicAdd(&stats[par * 256 + row * 2 + 1], q);
      }
    }
    // zero next-parity buffers one step ahead
    if (wgid == 0)      stats[npar * 256 + tid] = 0.0f;
    else if (wgid == 1) stats[(2 + npar) * 256 + tid] = 0.0f;
    grid.sync();

    // ================= B0: LN + LSTM cell, write h0 (2 fp16 planes) =========
    #pragma unroll
    for (int r = 0; r < 4; ++r) {
      int row = mtile * 16 + klo * 4 + r;
      float mean = stats[par * 256 + row * 2 + 0] * (1.0f / 4096.0f);
      float msq  = stats[par * 256 + row * 2 + 1] * (1.0f / 4096.0f);
      float rstd = rsqrtf(msq - mean * mean + 1e-5f);
      #pragma unroll
      for (int tl = 0; tl < 2; ++tl) {
        float gv = (tl == 0) ? a0[r] : a1[r];
        float gh = (gv - mean) * rstd * g0c[tl] + be0c[tl];
        float fg = __shfl_down(gh, 4);
        float gg = __shfl_down(gh, 8);
        float og = __shfl_down(gh, 12);
        if (c16 < 4) {
          float iv = sigm(gh), fv = sigm(fg), zv = tanh_fast(gg), ov = sigm(og);
          float cc = fv * c0s[tl][r] + iv * zv;
          c0s[tl][r] = cc;
          float hv = ov * tanh_fast(cc);
          int idx = row * 2048 + colgrp * 8 + tl * 4 + c16;
          _Float16 h1v = (_Float16)hv;
          hch[idx] = h1v;
          hcm[idx] = (_Float16)((hv - (float)h1v) * 2048.0f);
        }
      }
    }
    grid.sync();

    // ========= A1: gates1 = [h0_new, h1] @ W1slice (2-plane fp16 split) =====
    f32x4_t d0he = {0,0,0,0}, d0ho = {0,0,0,0}, d1he = {0,0,0,0}, d1ho = {0,0,0,0};
    f32x4_t d0me = {0,0,0,0}, d0mo = {0,0,0,0}, d1me = {0,0,0,0}, d1mo = {0,0,0,0};
    {
#define H1_BODY(KB, H0A, H1A, M0A, M1A) {                                     \
      half8_t ah = *(const half8_t*)&hrh[(KB) * 32 + klo * 8];                \
      half8_t am = *(const half8_t*)&hrm[(KB) * 32 + klo * 8];                \
      half8_t bh0 = *(const half8_t*)&w1a0[(KB) * 32 + klo * 8];              \
      half8_t bh1 = *(const half8_t*)&w1a1[(KB) * 32 + klo * 8];              \
      half8_t bm0 = *(const half8_t*)&w1b0[(KB) * 32 + klo * 8];              \
      half8_t bm1 = *(const half8_t*)&w1b1[(KB) * 32 + klo * 8];              \
      PROD6(H0A, H1A, M0A, M1A) }

      #pragma unroll 2
      for (int kb = 0; kb < 64; kb += 2) {
        H1_BODY(kb,     d0he, d1he, d0me, d1me);
        H1_BODY(kb + 1, d0ho, d1ho, d0mo, d1mo);
      }
#undef H1_BODY
    }
    f32x4_t d0 = (d0he + d0ho) * 0.03125f + (d0me + d0mo) * (1.0f / 65536.0f);
    f32x4_t d1 = (d1he + d1ho) * 0.03125f + (d1me + d1mo) * (1.0f / 65536.0f);
    #pragma unroll
    for (int r = 0; r < 4; ++r) { d0[r] += b1c[0]; d1[r] += b1c[1]; }
    #pragma unroll
    for (int r = 0; r < 4; ++r) {
      float s = d0[r] + d1[r];
      float q = d0[r]*d0[r] + d1[r]*d1[r];
      #pragma unroll
      for (int m = 1; m <= 8; m <<= 1) { s += __shfl_xor(s, m); q += __shfl_xor(q, m); }
      if (c16 == 0) {
        int row = mtile * 16 + klo * 4 + r;
        atomicAdd(&stats[(2 + par) * 256 + row * 2 + 0], s);
        atomicAdd(&stats[(2 + par) * 256 + row * 2 + 1], q);
      }
    }
    grid.sync();

    // ================= B1: LN + LSTM cell, write h1 (2 fp16 planes) =========
    #pragma unroll
    for (int r = 0; r < 4; ++r) {
      int row = mtile * 16 + klo * 4 + r;
      float mean = stats[(2 + par) * 256 + row * 2 + 0] * (1.0f / 4096.0f);
      float msq  = stats[(2 + par) * 256 + row * 2 + 1] * (1.0f / 4096.0f);
      float rstd = rsqrtf(msq - mean * mean + 1e-5f);
      #pragma unroll
      for (int tl = 0; tl < 2; ++tl) {
        float gv = (tl == 0) ? d0[r] : d1[r];
        float gh = (gv - mean) * rstd * g1c[tl] + be1c[tl];
        float fg = __shfl_down(gh, 4);
        float gg = __shfl_down(gh, 8);
        float og = __shfl_down(gh, 12);
        if (c16 < 4) {
          float iv = sigm(gh), fv = sigm(fg), zv = tanh_fast(gg), ov = sigm(og);
          float cc = fv * c1s[tl][r] + iv * zv;
          c1s[tl][r] = cc;
          float hv = ov * tanh_fast(cc);
          int idx = row * 2048 + 1024 + colgrp * 8 + tl * 4 + c16;
          _Float16 h1v = (_Float16)hv;
          hch[idx] = h1v;
          hcm[idx] = (_Float16)((hv - (float)h1v) * 2048.0f);
          if (t == 511) h1f32[row * 1024 + colgrp * 8 + tl * 4 + c16] = hv;
        }
      }
    }
    grid.sync();
  }

  // ================= final fc: out = h1 @ fcW + fcb (fp32) =================
  {
    int gid = wgid * 256 + tid;        // 65536 threads == 128*512 outputs
    int b = gid >> 9, o = gid & 511;
    const float* hr = h1f32 + b * 1024;
    float s = fcb[o];
    #pragma unroll 8
    for (int k = 0; k < 1024; ++k) s = fmaf(hr[k], fcW[k * 512 + o], s);
    out[gid] = s;
  }
}

extern "C" void kernel_launch(void* const* d_in, const int* in_sizes, int n_in,
                              void* d_out, int out_size, void* d_ws, size_t ws_size,
                              hipStream_t stream) {
  const float* x   = (const float*)d_in[0];
  const float* W0  = (const float*)d_in[1];
  const float* b0  = (const float*)d_in[2];
  const float* g0  = (const float*)d_in[3];
  const float* be0 = (const float*)d_in[4];
  const float* W1  = (const float*)d_in[5];
  const float* b1  = (const float*)d_in[6];
  const float* g1  = (const float*)d_in[7];
  const float* be1 = (const float*)d_in[8];
  const float* fcW = (const float*)d_in[9];
  const float* fcb = (const float*)d_in[10];
  float* out = (float*)d_out;

  char* ws = (char*)d_ws;
  _Float16* W0a  = (_Float16*)(ws);
  _Float16* W0b  = (_Float16*)(ws + 12582912);
  _Float16* W1a  = (_Float16*)(ws + 25165824);
  _Float16* W1b  = (_Float16*)(ws + 41943040);
  float* vecs    = (float*)(ws + 58720256);
  _Float16* hch  = (_Float16*)(ws + 58818560);
  _Float16* hcm  = (_Float16*)(ws + 59342848);
  float* stats   = (float*)(ws + 59867136);
  float* h1f32   = (float*)(ws + 59871232);

  // re-zero h planes + LN stat accumulators every call (graph replays reuse ws)
  hipMemsetAsync(hch, 0, 2 * 524288 + 4096, stream);
  lstm_prep<<<7264, 256, 0, stream>>>(W0, W1, b0, g0, be0, b1, g1, be1,
                                      W0a, W0b, W1a, W1b, vecs);

  hipFuncSetAttribute((const void*)lstm_seq,
                      hipFuncAttributeMaxDynamicSharedMemorySize, LDS_BYTES);
  void* args[] = { (void*)&x, (void*)&W0a, (void*)&W0b, (void*)&W1a, (void*)&W1b,
                   (void*)&vecs, (void*)&hch, (void*)&hcm,
                   (void*)&stats, (void*)&h1f32, (void*)&fcW, (void*)&fcb, (void*)&out };
  hipLaunchCooperativeKernel((const void*)lstm_seq, dim3(256), dim3(256),
                             args, LDS_BYTES, stream);
}

// Round 6
// 83693.524 us; speedup vs baseline: 1.4048x; 1.4048x over previous
//
#include <hip/hip_runtime.h>
#include <hip/hip_bf16.h>

typedef __attribute__((ext_vector_type(8))) _Float16 half8_t;
typedef __attribute__((ext_vector_type(4))) float f32x4_t;

#define S0W 1544                    // LDS row stride (elems): 1536 + 8 pad
#define LDS_BYTES (32 * S0W * 2)    // 98816 B (W0 plane-1 only)

__device__ __forceinline__ float sigm(float z) { return 1.0f / (1.0f + __expf(-z)); }
__device__ __forceinline__ float tanh_fast(float z) {
  float e = __expf(2.0f * z);
  return 1.0f - 2.0f / (e + 1.0f);
}

// ws layout (bytes) — total 59,904,000 < known-good 60,395,520:
//   W0a  @ 0         : 12582912   (fp16 plane1 = fp16(32*w), [gp][k])
//   W0b  @ 12582912  : 12582912   (fp16 plane2; h1f32 OVERLAYS its first 512KB —
//                                  h1f32 written only at t=511, 3 barriers after
//                                  the final W0b read)
//   W1a  @ 25165824  : 16777216
//   W1b  @ 41943040  : 16777216
//   vecs @ 58720256  : 98304      (b0,g0,be0,b1,g1,be1 permuted, fp32)
//   hch  @ 58818560  : 524288     (h plane1 fp16, [row][h0|h1])
//   hcm  @ 59342848  : 524288     (h plane2 fp16, residual*2048)
//   stats@ 59867136  : 32768      (8 reps x 4 bufs x 256 f32)  bufs: L0p0,L0p1,L1p0,L1p1
//   bars @ 59899904  : 4096       (barrier counters + release flag)

// permutation: gp = colgrp*32 + c ; tile=c>>4, cc=c&15, gate=cc>>2, uo=cc&3
//              gcol = gate*1024 + colgrp*8 + tile*4 + uo
__global__ void lstm_prep(const float* __restrict__ W0, const float* __restrict__ W1,
                          const float* __restrict__ b0, const float* __restrict__ g0,
                          const float* __restrict__ be0, const float* __restrict__ b1,
                          const float* __restrict__ g1, const float* __restrict__ be1,
                          _Float16* __restrict__ W0a, _Float16* __restrict__ W0b,
                          _Float16* __restrict__ W1a, _Float16* __restrict__ W1b,
                          float* __restrict__ vecs)
{
  int gid = blockIdx.x * 256 + threadIdx.x;
  const int W0N = 192 * 4096;
  const int W1N = 256 * 4096;
  if (gid < W0N) {
    int k8 = gid >> 12, gp = gid & 4095;
    int colgrp = gp >> 5, c = gp & 31;
    int tile = c >> 4, cc = c & 15;
    int gcol = ((cc >> 2) << 10) + (colgrp << 3) + (tile << 2) + (cc & 3);
    half8_t va, vb;
    #pragma unroll
    for (int j = 0; j < 8; ++j) {
      float w32 = W0[(size_t)(k8 * 8 + j) * 4096 + gcol] * 32.0f;
      _Float16 p1 = (_Float16)w32;
      float r = w32 - (float)p1;
      va[j] = p1; vb[j] = (_Float16)(r * 2048.0f);
    }
    *(half8_t*)&W0a[(size_t)gp * 1536 + k8 * 8] = va;
    *(half8_t*)&W0b[(size_t)gp * 1536 + k8 * 8] = vb;
  } else if (gid < W0N + W1N) {
    int g2 = gid - W0N;
    int k8 = g2 >> 12, gp = g2 & 4095;
    int colgrp = gp >> 5, c = gp & 31;
    int tile = c >> 4, cc = c & 15;
    int gcol = ((cc >> 2) << 10) + (colgrp << 3) + (tile << 2) + (cc & 3);
    half8_t va, vb;
    #pragma unroll
    for (int j = 0; j < 8; ++j) {
      float w32 = W1[(size_t)(k8 * 8 + j) * 4096 + gcol] * 32.0f;
      _Float16 p1 = (_Float16)w32;
      float r = w32 - (float)p1;
      va[j] = p1; vb[j] = (_Float16)(r * 2048.0f);
    }
    *(half8_t*)&W1a[(size_t)gp * 2048 + k8 * 8] = va;
    *(half8_t*)&W1b[(size_t)gp * 2048 + k8 * 8] = vb;
  } else if (gid < W0N + W1N + 6 * 4096) {
    int g2 = gid - W0N - W1N;
    int j = g2 >> 12, gp = g2 & 4095;
    int colgrp = gp >> 5, c = gp & 31;
    int tile = c >> 4, cc = c & 15;
    int gcol = ((cc >> 2) << 10) + (colgrp << 3) + (tile << 2) + (cc & 3);
    const float* src = (j == 0) ? b0 : (j == 1) ? g0 : (j == 2) ? be0
                     : (j == 3) ? b1 : (j == 4) ? g1 : be1;
    vecs[j * 4096 + gp] = src[gcol];
  }
}

#define MFMA16(A, B, C) __builtin_amdgcn_mfma_f32_16x16x32_f16(A, B, C, 0, 0, 0)

// ---- lightweight grid barrier: 8 sub-counters (32 arrivals each) -> master ->
// release flag; epoch-parity counter sets; agent-scope atomics; threadfence for
// cross-XCD visibility of normal stores (h planes, stat zeroing).
__device__ __forceinline__ void gridbar(unsigned* bars, int wgid, int tid, unsigned ep) {
  __threadfence();                 // release our h/zero stores device-wide
  __syncthreads();
  if (tid == 0) {
    const int q = ep & 1;
    unsigned old = __hip_atomic_fetch_add(&bars[(q * 8 + (wgid & 7)) * 32], 1u,
                                          __ATOMIC_ACQ_REL, __HIP_MEMORY_SCOPE_AGENT);
    if (old == 31u) {
      unsigned mo = __hip_atomic_fetch_add(&bars[512 + q * 32], 1u,
                                           __ATOMIC_ACQ_REL, __HIP_MEMORY_SCOPE_AGENT);
      if (mo == 7u) {
        #pragma unroll
        for (int g = 0; g < 8; ++g)
          __hip_atomic_store(&bars[(q * 8 + g) * 32], 0u, __ATOMIC_RELAXED, __HIP_MEMORY_SCOPE_AGENT);
        __hip_atomic_store(&bars[512 + q * 32], 0u, __ATOMIC_RELAXED, __HIP_MEMORY_SCOPE_AGENT);
        __hip_atomic_store(&bars[576], ep, __ATOMIC_RELEASE, __HIP_MEMORY_SCOPE_AGENT);
      }
    }
    while (__hip_atomic_load(&bars[576], __ATOMIC_RELAXED, __HIP_MEMORY_SCOPE_AGENT) < ep) {}
  }
  __syncthreads();
  __threadfence();                 // acquire: see others' stores
}

// persistent cooperative kernel: 256 WGs (128 colgrps x 2 m-halves) x 256 thr
// schedule: A0[0] | B0[0] | { alpha[t]={A1[t],A0[t+1]} | beta[t]={B1[t],B0[t+1]} }
// -> 2 barriers/step instead of 4.
__global__ void __launch_bounds__(256, 1) lstm_seq(
    const float* __restrict__ x,
    const _Float16* __restrict__ W0ap,
    const _Float16* __restrict__ W0bp,
    const _Float16* __restrict__ W1ap,
    const _Float16* __restrict__ W1bp,
    const float* __restrict__ vecs,
    _Float16* __restrict__ hch,
    _Float16* __restrict__ hcm,
    float* __restrict__ stats,
    unsigned* __restrict__ bars,
    float* __restrict__ h1f32,
    const float* __restrict__ fcW,
    const float* __restrict__ fcb,
    float* __restrict__ out)
{
  extern __shared__ _Float16 W0s[];   // [32][S0W] plane-1 (scaled x32)
  const int tid = threadIdx.x;
  const int wgid = blockIdx.x;
  const int colgrp = wgid & 127;
  const int mhalf = wgid >> 7;
  const int wid = tid >> 6;
  const int lane = tid & 63;
  const int c16 = lane & 15;
  const int klo = lane >> 4;

  for (int i = tid; i < 32 * 192; i += 256) {
    int r = i / 192, ch = i - r * 192;
    *(half8_t*)&W0s[r * S0W + ch * 8] =
        *(const half8_t*)&W0ap[((size_t)colgrp * 32 + r) * 1536 + ch * 8];
  }
  __syncthreads();

  float b0c[2], g0c[2], be0c[2], b1c[2], g1c[2], be1c[2];
  #pragma unroll
  for (int tl = 0; tl < 2; ++tl) {
    int gp = colgrp * 32 + tl * 16 + c16;
    b0c[tl]  = vecs[gp];
    g0c[tl]  = vecs[4096 + gp];
    be0c[tl] = vecs[8192 + gp];
    b1c[tl]  = vecs[12288 + gp];
    g1c[tl]  = vecs[16384 + gp];
    be1c[tl] = vecs[20480 + gp];
  }

  const int mtile = mhalf * 4 + wid;                 // 0..7
  const int arow = mtile * 16 + c16;
  const float* xbase = x + (size_t)arow * 512 * 512; // x[row][t][d]
  const _Float16* hrh = hch + arow * 2048;
  const _Float16* hrm = hcm + arow * 2048;
  const _Float16* w0m0 = W0bp + (size_t)(colgrp * 32 + c16) * 1536;
  const _Float16* w0m1 = w0m0 + (size_t)16 * 1536;
  const _Float16* w1a0 = W1ap + (size_t)(colgrp * 32 + c16) * 2048;
  const _Float16* w1a1 = w1a0 + (size_t)16 * 2048;
  const _Float16* w1b0 = W1bp + (size_t)(colgrp * 32 + c16) * 2048;
  const _Float16* w1b1 = w1b0 + (size_t)16 * 2048;
  const int repbase = (wgid & 7) << 2;               // rep*4 for stats

  float c0s[2][4] = {{0,0,0,0},{0,0,0,0}};
  float c1s[2][4] = {{0,0,0,0},{0,0,0,0}};
  unsigned ep = 0;

#define SPLIT2(E, J) { float e_ = (E); _Float16 h1_ = (_Float16)e_;           \
  float r_ = e_ - (float)h1_; ah[J] = h1_; am[J] = (_Float16)(r_ * 2048.0f); }

#define PROD6(H0A, H1A, M0A, M1A) \
  H0A = MFMA16(ah, bh0, H0A); H1A = MFMA16(ah, bh1, H1A);                     \
  M0A = MFMA16(ah, bm0, M0A); M1A = MFMA16(ah, bm1, M1A);                     \
  M0A = MFMA16(am, bh0, M0A); M1A = MFMA16(am, bh1, M1A);

#define X_BODY(KB, H0A, H1A, M0A, M1A) {                                      \
      float4 xu = *(const float4*)(xp + (KB) * 32);                           \
      float4 xw = *(const float4*)(xp + (KB) * 32 + 4);                       \
      half8_t ah, am;                                                         \
      SPLIT2(xu.x, 0) SPLIT2(xu.y, 1) SPLIT2(xu.z, 2) SPLIT2(xu.w, 3)         \
      SPLIT2(xw.x, 4) SPLIT2(xw.y, 5) SPLIT2(xw.z, 6) SPLIT2(xw.w, 7)         \
      half8_t bh0 = *(const half8_t*)&W0s[c16 * S0W + (KB) * 32 + klo * 8];   \
      half8_t bh1 = *(const half8_t*)&W0s[(16 + c16) * S0W + (KB) * 32 + klo * 8]; \
      half8_t bm0 = *(const half8_t*)&w0m0[(KB) * 32 + klo * 8];              \
      half8_t bm1 = *(const half8_t*)&w0m1[(KB) * 32 + klo * 8];              \
      PROD6(H0A, H1A, M0A, M1A) }

#define H0_BODY(KB, H0A, H1A, M0A, M1A) {                                     \
      half8_t ah = *(const half8_t*)&hrh[(KB) * 32 + klo * 8];                \
      half8_t am = *(const half8_t*)&hrm[(KB) * 32 + klo * 8];                \
      half8_t bh0 = *(const half8_t*)&W0s[c16 * S0W + 512 + (KB) * 32 + klo * 8]; \
      half8_t bh1 = *(const half8_t*)&W0s[(16 + c16) * S0W + 512 + (KB) * 32 + klo * 8]; \
      half8_t bm0 = *(const half8_t*)&w0m0[512 + (KB) * 32 + klo * 8];        \
      half8_t bm1 = *(const half8_t*)&w0m1[512 + (KB) * 32 + klo * 8];        \
      PROD6(H0A, H1A, M0A, M1A) }

#define H1_BODY(KB, H0A, H1A, M0A, M1A) {                                     \
      half8_t ah = *(const half8_t*)&hrh[(KB) * 32 + klo * 8];                \
      half8_t am = *(const half8_t*)&hrm[(KB) * 32 + klo * 8];                \
      half8_t bh0 = *(const half8_t*)&w1a0[(KB) * 32 + klo * 8];              \
      half8_t bh1 = *(const half8_t*)&w1a1[(KB) * 32 + klo * 8];              \
      half8_t bm0 = *(const half8_t*)&w1b0[(KB) * 32 + klo * 8];              \
      half8_t bm1 = *(const half8_t*)&w1b1[(KB) * 32 + klo * 8];              \
      PROD6(H0A, H1A, M0A, M1A) }

// accumulate LN partials of a 2-tile acc pair into stats buf (replicated).
// NOTE: inputs must already include the gate bias (reference LN is over Wx+b).
#define STAT_ADD(V0, V1, BUF) {                                               \
    _Pragma("unroll")                                                         \
    for (int r = 0; r < 4; ++r) {                                             \
      float s = V0[r] + V1[r];                                                \
      float q = V0[r]*V0[r] + V1[r]*V1[r];                                    \
      _Pragma("unroll")                                                       \
      for (int m = 1; m <= 8; m <<= 1) { s += __shfl_xor(s, m); q += __shfl_xor(q, m); } \
      if (c16 == 0) {                                                         \
        int row = mtile * 16 + klo * 4 + r;                                   \
        atomicAdd(&stats[(repbase + (BUF)) * 256 + row * 2 + 0], s);          \
        atomicAdd(&stats[(repbase + (BUF)) * 256 + row * 2 + 1], q);          \
      }                                                                       \
    } }

// LN + LSTM cell for one layer; V0/V1 are biased gate pre-norms.
#define CELL(V0, V1, BUF, CS, GC, BEC, HB, WRF32) {                           \
    _Pragma("unroll")                                                         \
    for (int r = 0; r < 4; ++r) {                                             \
      int row = mtile * 16 + klo * 4 + r;                                     \
      float s_ = 0.f, q_ = 0.f;                                               \
      _Pragma("unroll")                                                       \
      for (int rep = 0; rep < 8; ++rep) {                                     \
        const float* sp = stats + ((rep << 2) + (BUF)) * 256 + row * 2;       \
        s_ += sp[0]; q_ += sp[1];                                             \
      }                                                                       \
      float mean = s_ * (1.0f / 4096.0f);                                     \
      float msq  = q_ * (1.0f / 4096.0f);                                     \
      float rstd = rsqrtf(msq - mean * mean + 1e-5f);                         \
      _Pragma("unroll")                                                       \
      for (int tl = 0; tl < 2; ++tl) {                                        \
        float gv = (tl == 0) ? V0[r] : V1[r];                                 \
        float gh = (gv - mean) * rstd * GC[tl] + BEC[tl];                     \
        float fg = __shfl_down(gh, 4);                                        \
        float gg = __shfl_down(gh, 8);                                        \
        float og = __shfl_down(gh, 12);                                       \
        if (c16 < 4) {                                                        \
          float iv = sigm(gh), fv = sigm(fg), zv = tanh_fast(gg), ov = sigm(og); \
          float cc = fv * CS[tl][r] + iv * zv;                                \
          CS[tl][r] = cc;                                                     \
          float hv = ov * tanh_fast(cc);                                      \
          int idx = row * 2048 + (HB) + colgrp * 8 + tl * 4 + c16;            \
          _Float16 h1v = (_Float16)hv;                                        \
          hch[idx] = h1v;                                                     \
          hcm[idx] = (_Float16)((hv - (float)h1v) * 2048.0f);                 \
          if (WRF32) h1f32[row * 1024 + colgrp * 8 + tl * 4 + c16] = hv;      \
        }                                                                     \
      }                                                                       \
    } }

  // layer-0 accumulators (persist across barrier into beta's B0-part)
  f32x4_t a0he, a0ho, a1he, a1ho, a0me, a0mo, a1me, a1mo;
  // layer-1 accumulators
  f32x4_t d0he, d0ho, d1he, d1ho, d0me, d0mo, d1me, d1mo;
  f32x4_t a0, a1, d0, d1;

#define A0_COMPUTE(TT) {                                                      \
    a0he = {0,0,0,0}; a0ho = {0,0,0,0}; a1he = {0,0,0,0}; a1ho = {0,0,0,0};   \
    a0me = {0,0,0,0}; a0mo = {0,0,0,0}; a1me = {0,0,0,0}; a1mo = {0,0,0,0};   \
    const float* xp = xbase + (size_t)(TT) * 512 + klo * 8;                   \
    _Pragma("unroll 2")                                                       \
    for (int kb = 0; kb < 16; kb += 2) {                                      \
      X_BODY(kb,     a0he, a1he, a0me, a1me);                                 \
      X_BODY(kb + 1, a0ho, a1ho, a0mo, a1mo);                                 \
    }                                                                         \
    _Pragma("unroll 2")                                                       \
    for (int kb = 0; kb < 32; kb += 2) {                                      \
      H0_BODY(kb,     a0he, a1he, a0me, a1me);                                \
      H0_BODY(kb + 1, a0ho, a1ho, a0mo, a1mo);                                \
    }                                                                         \
    a0 = (a0he + a0ho) * 0.03125f + (a0me + a0mo) * (1.0f / 65536.0f);        \
    a1 = (a1he + a1ho) * 0.03125f + (a1me + a1mo) * (1.0f / 65536.0f);        \
    _Pragma("unroll")                                                         \
    for (int r_ = 0; r_ < 4; ++r_) { a0[r_] += b0c[0]; a1[r_] += b0c[1]; } }

  // ---------------- prologue: A0[0] ----------------
  A0_COMPUTE(0);
  STAT_ADD(a0, a1, 0);            // L0 parity 0 -> buf 0
  gridbar(bars, wgid, tid, ++ep);
  CELL(a0, a1, 0, c0s, g0c, be0c, 0, 0);   // B0[0] -> h0[0]
  gridbar(bars, wgid, tid, ++ep);

  // ---------------- main loop ----------------
  for (int t = 0; t < 512; ++t) {
    const int par = t & 1;
    const int npar = 1 - par;

    // ===== alpha[t]: A1[t] (+ A0[t+1]) =====
    d0he = {0,0,0,0}; d0ho = {0,0,0,0}; d1he = {0,0,0,0}; d1ho = {0,0,0,0};
    d0me = {0,0,0,0}; d0mo = {0,0,0,0}; d1me = {0,0,0,0}; d1mo = {0,0,0,0};
    #pragma unroll 2
    for (int kb = 0; kb < 64; kb += 2) {
      H1_BODY(kb,     d0he, d1he, d0me, d1me);
      H1_BODY(kb + 1, d0ho, d1ho, d0mo, d1mo);
    }
    d0 = (d0he + d0ho) * 0.03125f + (d0me + d0mo) * (1.0f / 65536.0f);
    d1 = (d1he + d1ho) * 0.03125f + (d1me + d1mo) * (1.0f / 65536.0f);
    #pragma unroll
    for (int r = 0; r < 4; ++r) { d0[r] += b1c[0]; d1[r] += b1c[1]; }
    STAT_ADD(d0, d1, 2 + par);    // L1 buf

    if (t < 511) {
      A0_COMPUTE(t + 1);
      STAT_ADD(a0, a1, npar);     // L0 buf, parity t+1
    }

    // zero the buffers alpha[t+1] will accumulate (consumed at beta[t-1])
    if (wgid < 8)       stats[((wgid << 2) + 2 + npar) * 256 + tid] = 0.0f;
    else if (wgid < 16) stats[(((wgid - 8) << 2) + par) * 256 + tid] = 0.0f;

    gridbar(bars, wgid, tid, ++ep);

    // ===== beta[t]: B1[t] (+ B0[t+1]) =====
    CELL(d0, d1, 2 + par, c1s, g1c, be1c, 1024, (t == 511));
    if (t < 511) {
      CELL(a0, a1, npar, c0s, g0c, be0c, 0, 0);
    }
    gridbar(bars, wgid, tid, ++ep);
  }

  // ---------------- final fc: out = h1 @ fcW + fcb (fp32) ----------------
  {
    int gid = wgid * 256 + tid;        // 65536 threads == 128*512 outputs
    int b = gid >> 9, o = gid & 511;
    const float* hr = h1f32 + b * 1024;
    float s = fcb[o];
    #pragma unroll 8
    for (int k = 0; k < 1024; ++k) s = fmaf(hr[k], fcW[k * 512 + o], s);
    out[gid] = s;
  }
}

extern "C" void kernel_launch(void* const* d_in, const int* in_sizes, int n_in,
                              void* d_out, int out_size, void* d_ws, size_t ws_size,
                              hipStream_t stream) {
  const float* x   = (const float*)d_in[0];
  const float* W0  = (const float*)d_in[1];
  const float* b0  = (const float*)d_in[2];
  const float* g0  = (const float*)d_in[3];
  const float* be0 = (const float*)d_in[4];
  const float* W1  = (const float*)d_in[5];
  const float* b1  = (const float*)d_in[6];
  const float* g1  = (const float*)d_in[7];
  const float* be1 = (const float*)d_in[8];
  const float* fcW = (const float*)d_in[9];
  const float* fcb = (const float*)d_in[10];
  float* out = (float*)d_out;

  char* ws = (char*)d_ws;
  _Float16* W0a  = (_Float16*)(ws);
  _Float16* W0b  = (_Float16*)(ws + 12582912);
  _Float16* W1a  = (_Float16*)(ws + 25165824);
  _Float16* W1b  = (_Float16*)(ws + 41943040);
  float* vecs    = (float*)(ws + 58720256);
  _Float16* hch  = (_Float16*)(ws + 58818560);
  _Float16* hcm  = (_Float16*)(ws + 59342848);
  float* stats   = (float*)(ws + 59867136);
  unsigned* bars = (unsigned*)(ws + 59899904);
  float* h1f32   = (float*)(ws + 12582912);   // overlays W0b (safe: see layout note)

  // re-zero h planes + stats + barrier state every call (graph replays reuse ws)
  hipMemsetAsync(hch, 0, 524288 + 524288 + 32768 + 4096, stream);
  lstm_prep<<<7264, 256, 0, stream>>>(W0, W1, b0, g0, be0, b1, g1, be1,
                                      W0a, W0b, W1a, W1b, vecs);

  hipFuncSetAttribute((const void*)lstm_seq,
                      hipFuncAttributeMaxDynamicSharedMemorySize, LDS_BYTES);
  void* args[] = { (void*)&x, (void*)&W0a, (void*)&W0b, (void*)&W1a, (void*)&W1b,
                   (void*)&vecs, (void*)&hch, (void*)&hcm,
                   (void*)&stats, (void*)&bars, (void*)&h1f32,
                   (void*)&fcW, (void*)&fcb, (void*)&out };
  hipLaunchCooperativeKernel((const void*)lstm_seq, dim3(256), dim3(256),
                             args, LDS_BYTES, stream);
}

// Round 7
// 56698.383 us; speedup vs baseline: 2.0737x; 1.4761x over previous
//
#include <hip/hip_runtime.h>
#include <hip/hip_bf16.h>

typedef __attribute__((ext_vector_type(8))) _Float16 half8_t;
typedef __attribute__((ext_vector_type(4))) float f32x4_t;
typedef unsigned long long u64;

#define S0W 1544                    // LDS row stride (elems): 1536 + 8 pad
#define LDS_BYTES (32 * S0W * 2)    // 98816 B (W0 plane-1 only)

__device__ __forceinline__ float sigm(float z) { return 1.0f / (1.0f + __expf(-z)); }
__device__ __forceinline__ float tanh_fast(float z) {
  float e = __expf(2.0f * z);
  return 1.0f - 2.0f / (e + 1.0f);
}

// ---- coherent (cross-XCD) access helpers: sc0/sc1 ops at the coherence point,
// compiler-tracked (no inline-asm waits -> MLP preserved).
__device__ __forceinline__ half8_t ld_h8_coh(const _Float16* p) {
  union { half8_t h; u64 q[2]; } r;
  u64* q = (u64*)p;
  r.q[0] = __hip_atomic_load(q,     __ATOMIC_RELAXED, __HIP_MEMORY_SCOPE_SYSTEM);
  r.q[1] = __hip_atomic_load(q + 1, __ATOMIC_RELAXED, __HIP_MEMORY_SCOPE_SYSTEM);
  return r.h;
}
__device__ __forceinline__ void st_h_coh(_Float16* p, _Float16 v) {
  unsigned short b = __builtin_bit_cast(unsigned short, v);
  __hip_atomic_store((unsigned short*)p, b, __ATOMIC_RELAXED, __HIP_MEMORY_SCOPE_SYSTEM);
}
__device__ __forceinline__ float ld_f_coh(const float* p) {
  return __hip_atomic_load((float*)p, __ATOMIC_RELAXED, __HIP_MEMORY_SCOPE_SYSTEM);
}
__device__ __forceinline__ void st_f_coh(float* p, float v) {
  __hip_atomic_store(p, v, __ATOMIC_RELAXED, __HIP_MEMORY_SCOPE_SYSTEM);
}

// ws layout (bytes) — total 59,904,000 (r6-identical, h1f32 eliminated):
//   W0a  @ 0         : 12582912   (fp16 plane1 = fp16(32*w), [gp][k])
//   W0b  @ 12582912  : 12582912
//   W1a  @ 25165824  : 16777216
//   W1b  @ 41943040  : 16777216
//   vecs @ 58720256  : 98304
//   hch  @ 58818560  : 524288     (h plane1 fp16, [row][h0|h1])
//   hcm  @ 59342848  : 524288     (h plane2 fp16, residual*2048)
//   stats@ 59867136  : 32768      (8 reps x 4 bufs x 256 f32)
//   bars @ 59899904  : 4096

__global__ void lstm_prep(const float* __restrict__ W0, const float* __restrict__ W1,
                          const float* __restrict__ b0, const float* __restrict__ g0,
                          const float* __restrict__ be0, const float* __restrict__ b1,
                          const float* __restrict__ g1, const float* __restrict__ be1,
                          _Float16* __restrict__ W0a, _Float16* __restrict__ W0b,
                          _Float16* __restrict__ W1a, _Float16* __restrict__ W1b,
                          float* __restrict__ vecs)
{
  int gid = blockIdx.x * 256 + threadIdx.x;
  const int W0N = 192 * 4096;
  const int W1N = 256 * 4096;
  if (gid < W0N) {
    int k8 = gid >> 12, gp = gid & 4095;
    int colgrp = gp >> 5, c = gp & 31;
    int tile = c >> 4, cc = c & 15;
    int gcol = ((cc >> 2) << 10) + (colgrp << 3) + (tile << 2) + (cc & 3);
    half8_t va, vb;
    #pragma unroll
    for (int j = 0; j < 8; ++j) {
      float w32 = W0[(size_t)(k8 * 8 + j) * 4096 + gcol] * 32.0f;
      _Float16 p1 = (_Float16)w32;
      float r = w32 - (float)p1;
      va[j] = p1; vb[j] = (_Float16)(r * 2048.0f);
    }
    *(half8_t*)&W0a[(size_t)gp * 1536 + k8 * 8] = va;
    *(half8_t*)&W0b[(size_t)gp * 1536 + k8 * 8] = vb;
  } else if (gid < W0N + W1N) {
    int g2 = gid - W0N;
    int k8 = g2 >> 12, gp = g2 & 4095;
    int colgrp = gp >> 5, c = gp & 31;
    int tile = c >> 4, cc = c & 15;
    int gcol = ((cc >> 2) << 10) + (colgrp << 3) + (tile << 2) + (cc & 3);
    half8_t va, vb;
    #pragma unroll
    for (int j = 0; j < 8; ++j) {
      float w32 = W1[(size_t)(k8 * 8 + j) * 4096 + gcol] * 32.0f;
      _Float16 p1 = (_Float16)w32;
      float r = w32 - (float)p1;
      va[j] = p1; vb[j] = (_Float16)(r * 2048.0f);
    }
    *(half8_t*)&W1a[(size_t)gp * 2048 + k8 * 8] = va;
    *(half8_t*)&W1b[(size_t)gp * 2048 + k8 * 8] = vb;
  } else if (gid < W0N + W1N + 6 * 4096) {
    int g2 = gid - W0N - W1N;
    int j = g2 >> 12, gp = g2 & 4095;
    int colgrp = gp >> 5, c = gp & 31;
    int tile = c >> 4, cc = c & 15;
    int gcol = ((cc >> 2) << 10) + (colgrp << 3) + (tile << 2) + (cc & 3);
    const float* src = (j == 0) ? b0 : (j == 1) ? g0 : (j == 2) ? be0
                     : (j == 3) ? b1 : (j == 4) ? g1 : be1;
    vecs[j * 4096 + gp] = src[gcol];
  }
}

#define MFMA16(A, B, C) __builtin_amdgcn_mfma_f32_16x16x32_f16(A, B, C, 0, 0, 0)

// ---- FENCE-FREE grid barrier. No __threadfence (no L2 invalidate/writeback):
// all cross-WG data moves via sc0/sc1 coherent ops, so L2 keeps weights warm.
// __syncthreads drains each thread's outstanding (coherent) stores first.
__device__ __forceinline__ void gridbar(unsigned* bars, int wgid, int tid, unsigned ep) {
  __syncthreads();
  if (tid == 0) {
    const int q = ep & 1;
    unsigned old = __hip_atomic_fetch_add(&bars[(q * 8 + (wgid & 7)) * 32], 1u,
                                          __ATOMIC_RELAXED, __HIP_MEMORY_SCOPE_AGENT);
    if (old == 31u) {
      unsigned mo = __hip_atomic_fetch_add(&bars[512 + q * 32], 1u,
                                           __ATOMIC_RELAXED, __HIP_MEMORY_SCOPE_AGENT);
      if (mo == 7u) {
        #pragma unroll
        for (int g = 0; g < 8; ++g)
          __hip_atomic_store(&bars[(q * 8 + g) * 32], 0u, __ATOMIC_RELAXED, __HIP_MEMORY_SCOPE_SYSTEM);
        __hip_atomic_store(&bars[512 + q * 32], 0u, __ATOMIC_RELAXED, __HIP_MEMORY_SCOPE_SYSTEM);
        __hip_atomic_store(&bars[576], ep, __ATOMIC_RELEASE, __HIP_MEMORY_SCOPE_SYSTEM);
      }
    }
    while (__hip_atomic_load(&bars[576], __ATOMIC_RELAXED, __HIP_MEMORY_SCOPE_SYSTEM) < ep) {}
  }
  __syncthreads();
}

__global__ void __launch_bounds__(256, 1) lstm_seq(
    const float* __restrict__ x,
    const _Float16* __restrict__ W0ap,
    const _Float16* __restrict__ W0bp,
    const _Float16* __restrict__ W1ap,
    const _Float16* __restrict__ W1bp,
    const float* __restrict__ vecs,
    _Float16* __restrict__ hch,
    _Float16* __restrict__ hcm,
    float* __restrict__ stats,
    unsigned* __restrict__ bars,
    const float* __restrict__ fcW,
    const float* __restrict__ fcb,
    float* __restrict__ out)
{
  extern __shared__ _Float16 W0s[];   // [32][S0W] plane-1 (scaled x32)
  const int tid = threadIdx.x;
  const int wgid = blockIdx.x;
  const int colgrp = wgid & 127;
  const int mhalf = wgid >> 7;
  const int wid = tid >> 6;
  const int lane = tid & 63;
  const int c16 = lane & 15;
  const int klo = lane >> 4;

  for (int i = tid; i < 32 * 192; i += 256) {
    int r = i / 192, ch = i - r * 192;
    *(half8_t*)&W0s[r * S0W + ch * 8] =
        *(const half8_t*)&W0ap[((size_t)colgrp * 32 + r) * 1536 + ch * 8];
  }
  __syncthreads();

  float b0c[2], g0c[2], be0c[2], b1c[2], g1c[2], be1c[2];
  #pragma unroll
  for (int tl = 0; tl < 2; ++tl) {
    int gp = colgrp * 32 + tl * 16 + c16;
    b0c[tl]  = vecs[gp];
    g0c[tl]  = vecs[4096 + gp];
    be0c[tl] = vecs[8192 + gp];
    b1c[tl]  = vecs[12288 + gp];
    g1c[tl]  = vecs[16384 + gp];
    be1c[tl] = vecs[20480 + gp];
  }

  const int mtile = mhalf * 4 + wid;                 // 0..7
  const int arow = mtile * 16 + c16;
  const float* xbase = x + (size_t)arow * 512 * 512; // x[row][t][d]
  const _Float16* hrh = hch + arow * 2048;
  const _Float16* hrm = hcm + arow * 2048;
  const _Float16* w0m0 = W0bp + (size_t)(colgrp * 32 + c16) * 1536;
  const _Float16* w0m1 = w0m0 + (size_t)16 * 1536;
  const _Float16* w1a0 = W1ap + (size_t)(colgrp * 32 + c16) * 2048;
  const _Float16* w1a1 = w1a0 + (size_t)16 * 2048;
  const _Float16* w1b0 = W1bp + (size_t)(colgrp * 32 + c16) * 2048;
  const _Float16* w1b1 = w1b0 + (size_t)16 * 2048;
  const int repbase = (wgid & 7) << 2;               // rep*4 for stats

  float c0s[2][4] = {{0,0,0,0},{0,0,0,0}};
  float c1s[2][4] = {{0,0,0,0},{0,0,0,0}};
  unsigned ep = 0;

#define SPLIT2(E, J) { float e_ = (E); _Float16 h1_ = (_Float16)e_;           \
  float r_ = e_ - (float)h1_; ah[J] = h1_; am[J] = (_Float16)(r_ * 2048.0f); }

#define PROD6(H0A, H1A, M0A, M1A) \
  H0A = MFMA16(ah, bh0, H0A); H1A = MFMA16(ah, bh1, H1A);                     \
  M0A = MFMA16(ah, bm0, M0A); M1A = MFMA16(ah, bm1, M1A);                     \
  M0A = MFMA16(am, bh0, M0A); M1A = MFMA16(am, bh1, M1A);

#define X_BODY(KB, H0A, H1A, M0A, M1A) {                                      \
      float4 xu = *(const float4*)(xp + (KB) * 32);                           \
      float4 xw = *(const float4*)(xp + (KB) * 32 + 4);                       \
      half8_t ah, am;                                                         \
      SPLIT2(xu.x, 0) SPLIT2(xu.y, 1) SPLIT2(xu.z, 2) SPLIT2(xu.w, 3)         \
      SPLIT2(xw.x, 4) SPLIT2(xw.y, 5) SPLIT2(xw.z, 6) SPLIT2(xw.w, 7)         \
      half8_t bh0 = *(const half8_t*)&W0s[c16 * S0W + (KB) * 32 + klo * 8];   \
      half8_t bh1 = *(const half8_t*)&W0s[(16 + c16) * S0W + (KB) * 32 + klo * 8]; \
      half8_t bm0 = *(const half8_t*)&w0m0[(KB) * 32 + klo * 8];              \
      half8_t bm1 = *(const half8_t*)&w0m1[(KB) * 32 + klo * 8];              \
      PROD6(H0A, H1A, M0A, M1A) }

#define H0_BODY(KB, H0A, H1A, M0A, M1A) {                                     \
      half8_t ah = ld_h8_coh(&hrh[(KB) * 32 + klo * 8]);                      \
      half8_t am = ld_h8_coh(&hrm[(KB) * 32 + klo * 8]);                      \
      half8_t bh0 = *(const half8_t*)&W0s[c16 * S0W + 512 + (KB) * 32 + klo * 8]; \
      half8_t bh1 = *(const half8_t*)&W0s[(16 + c16) * S0W + 512 + (KB) * 32 + klo * 8]; \
      half8_t bm0 = *(const half8_t*)&w0m0[512 + (KB) * 32 + klo * 8];        \
      half8_t bm1 = *(const half8_t*)&w0m1[512 + (KB) * 32 + klo * 8];        \
      PROD6(H0A, H1A, M0A, M1A) }

#define H1_BODY(KB, H0A, H1A, M0A, M1A) {                                     \
      half8_t ah = ld_h8_coh(&hrh[(KB) * 32 + klo * 8]);                      \
      half8_t am = ld_h8_coh(&hrm[(KB) * 32 + klo * 8]);                      \
      half8_t bh0 = *(const half8_t*)&w1a0[(KB) * 32 + klo * 8];              \
      half8_t bh1 = *(const half8_t*)&w1a1[(KB) * 32 + klo * 8];              \
      half8_t bm0 = *(const half8_t*)&w1b0[(KB) * 32 + klo * 8];              \
      half8_t bm1 = *(const half8_t*)&w1b1[(KB) * 32 + klo * 8];              \
      PROD6(H0A, H1A, M0A, M1A) }

#define STAT_ADD(V0, V1, BUF) {                                               \
    _Pragma("unroll")                                                         \
    for (int r = 0; r < 4; ++r) {                                             \
      float s = V0[r] + V1[r];                                                \
      float q = V0[r]*V0[r] + V1[r]*V1[r];                                    \
      _Pragma("unroll")                                                       \
      for (int m = 1; m <= 8; m <<= 1) { s += __shfl_xor(s, m); q += __shfl_xor(q, m); } \
      if (c16 == 0) {                                                         \
        int row = mtile * 16 + klo * 4 + r;                                   \
        atomicAdd(&stats[(repbase + (BUF)) * 256 + row * 2 + 0], s);          \
        atomicAdd(&stats[(repbase + (BUF)) * 256 + row * 2 + 1], q);          \
      }                                                                       \
    } }

// LN + LSTM cell; V0/V1 are biased gate pre-norms. Coherent stats reads,
// coherent h-plane stores.
#define CELL(V0, V1, BUF, CS, GC, BEC, HB) {                                  \
    _Pragma("unroll")                                                         \
    for (int r = 0; r < 4; ++r) {                                             \
      int row = mtile * 16 + klo * 4 + r;                                     \
      float s_ = 0.f, q_ = 0.f;                                               \
      _Pragma("unroll")                                                       \
      for (int rep = 0; rep < 8; ++rep) {                                     \
        const float* sp = stats + ((rep << 2) + (BUF)) * 256 + row * 2;       \
        s_ += ld_f_coh(sp); q_ += ld_f_coh(sp + 1);                           \
      }                                                                       \
      float mean = s_ * (1.0f / 4096.0f);                                     \
      float msq  = q_ * (1.0f / 4096.0f);                                     \
      float rstd = rsqrtf(msq - mean * mean + 1e-5f);                         \
      _Pragma("unroll")                                                       \
      for (int tl = 0; tl < 2; ++tl) {                                        \
        float gv = (tl == 0) ? V0[r] : V1[r];                                 \
        float gh = (gv - mean) * rstd * GC[tl] + BEC[tl];                     \
        float fg = __shfl_down(gh, 4);                                        \
        float gg = __shfl_down(gh, 8);                                        \
        float og = __shfl_down(gh, 12);                                       \
        if (c16 < 4) {                                                        \
          float iv = sigm(gh), fv = sigm(fg), zv = tanh_fast(gg), ov = sigm(og); \
          float cc = fv * CS[tl][r] + iv * zv;                                \
          CS[tl][r] = cc;                                                     \
          float hv = ov * tanh_fast(cc);                                      \
          int idx = row * 2048 + (HB) + colgrp * 8 + tl * 4 + c16;            \
          _Float16 h1v = (_Float16)hv;                                        \
          st_h_coh(&hch[idx], h1v);                                           \
          st_h_coh(&hcm[idx], (_Float16)((hv - (float)h1v) * 2048.0f));       \
        }                                                                     \
      }                                                                       \
    } }

  f32x4_t a0he, a0ho, a1he, a1ho, a0me, a0mo, a1me, a1mo;
  f32x4_t d0he, d0ho, d1he, d1ho, d0me, d0mo, d1me, d1mo;
  f32x4_t a0, a1, d0, d1;

#define A0_COMPUTE(TT) {                                                      \
    a0he = {0,0,0,0}; a0ho = {0,0,0,0}; a1he = {0,0,0,0}; a1ho = {0,0,0,0};   \
    a0me = {0,0,0,0}; a0mo = {0,0,0,0}; a1me = {0,0,0,0}; a1mo = {0,0,0,0};   \
    const float* xp = xbase + (size_t)(TT) * 512 + klo * 8;                   \
    _Pragma("unroll 2")                                                       \
    for (int kb = 0; kb < 16; kb += 2) {                                      \
      X_BODY(kb,     a0he, a1he, a0me, a1me);                                 \
      X_BODY(kb + 1, a0ho, a1ho, a0mo, a1mo);                                 \
    }                                                                         \
    _Pragma("unroll 2")                                                       \
    for (int kb = 0; kb < 32; kb += 2) {                                      \
      H0_BODY(kb,     a0he, a1he, a0me, a1me);                                \
      H0_BODY(kb + 1, a0ho, a1ho, a0mo, a1mo);                                \
    }                                                                         \
    a0 = (a0he + a0ho) * 0.03125f + (a0me + a0mo) * (1.0f / 65536.0f);        \
    a1 = (a1he + a1ho) * 0.03125f + (a1me + a1mo) * (1.0f / 65536.0f);        \
    _Pragma("unroll")                                                         \
    for (int r_ = 0; r_ < 4; ++r_) { a0[r_] += b0c[0]; a1[r_] += b0c[1]; } }

  // ---------------- prologue: A0[0] ----------------
  A0_COMPUTE(0);
  STAT_ADD(a0, a1, 0);
  gridbar(bars, wgid, tid, ++ep);
  CELL(a0, a1, 0, c0s, g0c, be0c, 0);
  gridbar(bars, wgid, tid, ++ep);

  // ---------------- main loop ----------------
  for (int t = 0; t < 512; ++t) {
    const int par = t & 1;
    const int npar = 1 - par;

    // ===== alpha[t]: A1[t] (+ A0[t+1]) =====
    d0he = {0,0,0,0}; d0ho = {0,0,0,0}; d1he = {0,0,0,0}; d1ho = {0,0,0,0};
    d0me = {0,0,0,0}; d0mo = {0,0,0,0}; d1me = {0,0,0,0}; d1mo = {0,0,0,0};
    #pragma unroll 2
    for (int kb = 0; kb < 64; kb += 2) {
      H1_BODY(kb,     d0he, d1he, d0me, d1me);
      H1_BODY(kb + 1, d0ho, d1ho, d0mo, d1mo);
    }
    d0 = (d0he + d0ho) * 0.03125f + (d0me + d0mo) * (1.0f / 65536.0f);
    d1 = (d1he + d1ho) * 0.03125f + (d1me + d1mo) * (1.0f / 65536.0f);
    #pragma unroll
    for (int r = 0; r < 4; ++r) { d0[r] += b1c[0]; d1[r] += b1c[1]; }
    STAT_ADD(d0, d1, 2 + par);

    if (t < 511) {
      A0_COMPUTE(t + 1);
      STAT_ADD(a0, a1, npar);
    }

    // zero the buffers alpha[t+1] will accumulate (coherent stores; ordering
    // vs other WGs' atomicAdds provided by the intervening gridbar)
    if (wgid < 8)       st_f_coh(&stats[((wgid << 2) + 2 + npar) * 256 + tid], 0.0f);
    else if (wgid < 16) st_f_coh(&stats[(((wgid - 8) << 2) + par) * 256 + tid], 0.0f);

    gridbar(bars, wgid, tid, ++ep);

    // ===== beta[t]: B1[t] (+ B0[t+1]) =====
    CELL(d0, d1, 2 + par, c1s, g1c, be1c, 1024);
    if (t < 511) {
      CELL(a0, a1, npar, c0s, g0c, be0c, 0);
    }
    gridbar(bars, wgid, tid, ++ep);
  }

  // ---------------- final fc: out = h1 @ fcW + fcb ----------------
  // h1 reconstructed from the two fp16 planes (22-bit): h = p1 + p2/2048.
  {
    int gid = wgid * 256 + tid;        // 65536 threads == 128*512 outputs
    int b = gid >> 9, o = gid & 511;
    const _Float16* p1 = hch + (size_t)b * 2048 + 1024;
    const _Float16* p2 = hcm + (size_t)b * 2048 + 1024;
    float s = fcb[o];
    #pragma unroll 4
    for (int k = 0; k < 1024; k += 4) {
      union { u64 q; _Float16 h[4]; } ua, um;
      ua.q = __hip_atomic_load((u64*)(p1 + k), __ATOMIC_RELAXED, __HIP_MEMORY_SCOPE_SYSTEM);
      um.q = __hip_atomic_load((u64*)(p2 + k), __ATOMIC_RELAXED, __HIP_MEMORY_SCOPE_SYSTEM);
      #pragma unroll
      for (int i = 0; i < 4; ++i) {
        float h = (float)ua.h[i] + (float)um.h[i] * (1.0f / 2048.0f);
        s = fmaf(h, fcW[(k + i) * 512 + o], s);
      }
    }
    out[gid] = s;
  }
}

extern "C" void kernel_launch(void* const* d_in, const int* in_sizes, int n_in,
                              void* d_out, int out_size, void* d_ws, size_t ws_size,
                              hipStream_t stream) {
  const float* x   = (const float*)d_in[0];
  const float* W0  = (const float*)d_in[1];
  const float* b0  = (const float*)d_in[2];
  const float* g0  = (const float*)d_in[3];
  const float* be0 = (const float*)d_in[4];
  const float* W1  = (const float*)d_in[5];
  const float* b1  = (const float*)d_in[6];
  const float* g1  = (const float*)d_in[7];
  const float* be1 = (const float*)d_in[8];
  const float* fcW = (const float*)d_in[9];
  const float* fcb = (const float*)d_in[10];
  float* out = (float*)d_out;

  char* ws = (char*)d_ws;
  _Float16* W0a  = (_Float16*)(ws);
  _Float16* W0b  = (_Float16*)(ws + 12582912);
  _Float16* W1a  = (_Float16*)(ws + 25165824);
  _Float16* W1b  = (_Float16*)(ws + 41943040);
  float* vecs    = (float*)(ws + 58720256);
  _Float16* hch  = (_Float16*)(ws + 58818560);
  _Float16* hcm  = (_Float16*)(ws + 59342848);
  float* stats   = (float*)(ws + 59867136);
  unsigned* bars = (unsigned*)(ws + 59899904);

  // re-zero h planes + stats + barrier state every call (graph replays reuse ws)
  hipMemsetAsync(hch, 0, 524288 + 524288 + 32768 + 4096, stream);
  lstm_prep<<<7264, 256, 0, stream>>>(W0, W1, b0, g0, be0, b1, g1, be1,
                                      W0a, W0b, W1a, W1b, vecs);

  hipFuncSetAttribute((const void*)lstm_seq,
                      hipFuncAttributeMaxDynamicSharedMemorySize, LDS_BYTES);
  void* args[] = { (void*)&x, (void*)&W0a, (void*)&W0b, (void*)&W1a, (void*)&W1b,
                   (void*)&vecs, (void*)&hch, (void*)&hcm,
                   (void*)&stats, (void*)&bars,
                   (void*)&fcW, (void*)&fcb, (void*)&out };
  hipLaunchCooperativeKernel((const void*)lstm_seq, dim3(256), dim3(256),
                             args, LDS_BYTES, stream);
}